// Round 1
// baseline (6270.721 us; speedup 1.0000x reference)
//
#include <hip/hip_runtime.h>
#include <cstdint>
#include <cstddef>

// Problem constants (match reference)
#define N_ROWS 65536
#define K_CODES 4096
#define DIM 512
#define ND_OUT ((size_t)N_ROWS * DIM)   // 33554432

// d_out layout (float32): [0,N*D) z_q | [N*D, N*D+N) indices-as-float | perplexity | alpha
// d_ws layout (bytes):
//   packed u64 [N]  @ 0         (monotone-float(max)<<32 | ~argmax)  -- zero-init ok
//   ssum   f32 [N]  @ 524288    (sum of exp(logit) per row)          -- zero-init
//   avgp   f32 [K]  @ 786432    (sum over n of exp(l)/s_n)           -- zero-init
//   arn    f32 [N]  @ 802816    (logit_scale / max(||z_n||,eps))
//   brn    f32 [K]  @ 1064960   (1 / max(||e_k||,eps))

__device__ inline unsigned long long pack_max(float v, unsigned idx) {
    unsigned u = __float_as_uint(v);
    u = (u & 0x80000000u) ? ~u : (u | 0x80000000u);   // monotone map, handles negatives
    return ((unsigned long long)u << 32) | (unsigned)(~idx);  // tie -> smaller idx wins
}

// One wave per row: sum of squares over 512 floats -> scale / max(sqrt, 1e-12)
__global__ __launch_bounds__(256) void rownorm_kernel(const float* __restrict__ x,
                                                      float* __restrict__ out,
                                                      const float* __restrict__ scale_ptr) {
    int lane = threadIdx.x & 63;
    int row  = blockIdx.x * 4 + (threadIdx.x >> 6);
    const float4* x4 = reinterpret_cast<const float4*>(x) + (size_t)row * (DIM / 4);
    float4 v0 = x4[lane];
    float4 v1 = x4[64 + lane];
    float s = v0.x*v0.x + v0.y*v0.y + v0.z*v0.z + v0.w*v0.w
            + v1.x*v1.x + v1.y*v1.y + v1.z*v1.z + v1.w*v1.w;
#pragma unroll
    for (int off = 32; off; off >>= 1) s += __shfl_xor(s, off);
    if (lane == 0) {
        float scale = scale_ptr ? scale_ptr[0] : 1.0f;
        out[row] = scale / fmaxf(sqrtf(s), 1e-12f);
    }
}

// Tiled fp32 GEMM: C = A(z_e) . B(emb)^T, scaled in epilogue by arn[row]*brn[col].
// 128x128 tile, 256 threads, 8x8 micro-tile (split 4+4 halves), BK=16.
// PASS==1: per-row (max,argmax) via packed atomicMax + sumexp via atomicAdd.
// PASS==2: per-col sum of exp(l)/ssum[row] -> atomicAdd into avgp.
template <int PASS>
__global__ __launch_bounds__(256) void gemm_pass(
        const float* __restrict__ A, const float* __restrict__ B,
        const float* __restrict__ arn, const float* __restrict__ brn,
        unsigned long long* __restrict__ packed, float* __restrict__ ssum,
        float* __restrict__ avgp) {
    __shared__ __align__(16) float As[16][132];
    __shared__ __align__(16) float Bs[16][132];
    const int tid = threadIdx.x;
    const int tr = tid >> 4, tc = tid & 15;
    const int row0 = blockIdx.y * 128, col0 = blockIdx.x * 128;

    float acc[8][8] = {};
    const float4* A4 = reinterpret_cast<const float4*>(A);
    const float4* B4 = reinterpret_cast<const float4*>(B);

    for (int d0 = 0; d0 < DIM; d0 += 16) {
#pragma unroll
        for (int l = 0; l < 2; ++l) {
            int q = tid + l * 256;          // 0..511  (128 rows x 4 float4)
            int r = q >> 2, dq = q & 3;
            float4 av = A4[(size_t)(row0 + r) * (DIM / 4) + (d0 >> 2) + dq];
            float4 bv = B4[(size_t)(col0 + r) * (DIM / 4) + (d0 >> 2) + dq];
            As[dq*4+0][r] = av.x; As[dq*4+1][r] = av.y; As[dq*4+2][r] = av.z; As[dq*4+3][r] = av.w;
            Bs[dq*4+0][r] = bv.x; Bs[dq*4+1][r] = bv.y; Bs[dq*4+2][r] = bv.z; Bs[dq*4+3][r] = bv.w;
        }
        __syncthreads();
#pragma unroll
        for (int dd = 0; dd < 16; ++dd) {
            float4 a0 = *reinterpret_cast<const float4*>(&As[dd][tr * 4]);
            float4 a1 = *reinterpret_cast<const float4*>(&As[dd][64 + tr * 4]);
            float4 b0 = *reinterpret_cast<const float4*>(&Bs[dd][tc * 4]);
            float4 b1 = *reinterpret_cast<const float4*>(&Bs[dd][64 + tc * 4]);
            float av[8] = {a0.x, a0.y, a0.z, a0.w, a1.x, a1.y, a1.z, a1.w};
            float bv[8] = {b0.x, b0.y, b0.z, b0.w, b1.x, b1.y, b1.z, b1.w};
#pragma unroll
            for (int i = 0; i < 8; ++i)
#pragma unroll
                for (int j = 0; j < 8; ++j)
                    acc[i][j] = fmaf(av[i], bv[j], acc[i][j]);
        }
        __syncthreads();
    }

    int rows[8], cols[8];
    float ar[8], bc[8];
#pragma unroll
    for (int i = 0; i < 8; ++i) {
        rows[i] = (i < 4) ? (tr * 4 + i) : (64 + tr * 4 + i - 4);
        ar[i] = arn[row0 + rows[i]];
    }
#pragma unroll
    for (int j = 0; j < 8; ++j) {
        cols[j] = (j < 4) ? (tc * 4 + j) : (64 + tc * 4 + j - 4);
        bc[j] = brn[col0 + cols[j]];
    }

    if constexpr (PASS == 1) {
#pragma unroll
        for (int i = 0; i < 8; ++i) {
            float m = -1e30f; int mi = 0; float se = 0.0f;
#pragma unroll
            for (int j = 0; j < 8; ++j) {
                float l = acc[i][j] * ar[i] * bc[j];
                int c = col0 + cols[j];
                if (l > m || (l == m && c < mi)) { m = l; mi = c; }
                se += expf(l);
            }
            // reduce across the 16 threads (same tr) owning this row
#pragma unroll
            for (int off = 1; off < 16; off <<= 1) {
                float om = __shfl_xor(m, off, 16);
                int   oi = __shfl_xor(mi, off, 16);
                float os = __shfl_xor(se, off, 16);
                se += os;
                if (om > m || (om == m && oi < mi)) { m = om; mi = oi; }
            }
            if (tc == 0) {
                int grow = row0 + rows[i];
                atomicMax(packed + grow, pack_max(m, (unsigned)mi));
                atomicAdd(&ssum[grow], se);
            }
        }
    } else {
        float sinv[8];
#pragma unroll
        for (int i = 0; i < 8; ++i) sinv[i] = 1.0f / ssum[row0 + rows[i]];
        float cp[8] = {};
#pragma unroll
        for (int i = 0; i < 8; ++i)
#pragma unroll
            for (int j = 0; j < 8; ++j)
                cp[j] += expf(acc[i][j] * ar[i] * bc[j]) * sinv[i];
        __syncthreads();                      // done with As/Bs tiles
        float* red = &As[0][0];               // reuse LDS: [16][128] partials
#pragma unroll
        for (int j = 0; j < 8; ++j) red[tr * 128 + cols[j]] = cp[j];
        __syncthreads();
        if (tid < 128) {
            float s = 0.0f;
#pragma unroll
            for (int t = 0; t < 16; ++t) s += red[t * 128 + tid];
            atomicAdd(&avgp[col0 + tid], s);
        }
    }
}

// z_q = alpha*emb[idx] + (1-alpha)*z_e ; also writes indices (as float)
__global__ __launch_bounds__(256) void zq_kernel(const float* __restrict__ ze,
                                                 const float* __restrict__ emb,
                                                 const unsigned long long* __restrict__ packed,
                                                 const float* __restrict__ resw,
                                                 float* __restrict__ out) {
    int q = blockIdx.x * 256 + threadIdx.x;   // < N * 128
    int n = q >> 7, d4 = q & 127;
    unsigned idx = ~(unsigned)(packed[n] & 0xFFFFFFFFull);
    float alpha = 1.0f / (1.0f + expf(-resw[0]));
    float4 e = reinterpret_cast<const float4*>(emb)[(size_t)idx * 128 + d4];
    float4 z = reinterpret_cast<const float4*>(ze)[(size_t)n * 128 + d4];
    float4 o;
    o.x = alpha * e.x + (1.0f - alpha) * z.x;
    o.y = alpha * e.y + (1.0f - alpha) * z.y;
    o.z = alpha * e.z + (1.0f - alpha) * z.z;
    o.w = alpha * e.w + (1.0f - alpha) * z.w;
    reinterpret_cast<float4*>(out)[(size_t)n * 128 + d4] = o;
    if (d4 == 0) out[ND_OUT + n] = (float)idx;
}

__global__ __launch_bounds__(256) void finalize_kernel(const float* __restrict__ avgp,
                                                       const float* __restrict__ resw,
                                                       float* __restrict__ out) {
    float acc = 0.0f;
    for (int k = threadIdx.x; k < K_CODES; k += 256) {
        float p = avgp[k] * (1.0f / (float)N_ROWS);
        acc += p * logf(p + 1e-10f);
    }
    __shared__ float red[4];
#pragma unroll
    for (int off = 32; off; off >>= 1) acc += __shfl_xor(acc, off);
    int lane = threadIdx.x & 63, wave = threadIdx.x >> 6;
    if (lane == 0) red[wave] = acc;
    __syncthreads();
    if (threadIdx.x == 0) {
        float s = red[0] + red[1] + red[2] + red[3];
        out[ND_OUT + N_ROWS]     = expf(-s);                       // perplexity
        out[ND_OUT + N_ROWS + 1] = 1.0f / (1.0f + expf(-resw[0])); // alpha
    }
}

extern "C" void kernel_launch(void* const* d_in, const int* in_sizes, int n_in,
                              void* d_out, int out_size, void* d_ws, size_t ws_size,
                              hipStream_t stream) {
    const float* ze   = (const float*)d_in[0];
    const float* emb  = (const float*)d_in[1];
    const float* ls   = (const float*)d_in[2];
    const float* resw = (const float*)d_in[3];
    float* out = (float*)d_out;

    char* ws = (char*)d_ws;
    unsigned long long* packed = (unsigned long long*)(ws + 0);
    float* ssum = (float*)(ws + 524288);
    float* avgp = (float*)(ws + 786432);
    float* arn  = (float*)(ws + 802816);
    float* brn  = (float*)(ws + 1064960);

    // zero accumulators (packed|ssum|avgp are contiguous)
    hipMemsetAsync(d_ws, 0, 802816, stream);

    rownorm_kernel<<<N_ROWS / 4, 256, 0, stream>>>(ze, arn, ls);
    rownorm_kernel<<<K_CODES / 4, 256, 0, stream>>>(emb, brn, nullptr);

    dim3 grid(K_CODES / 128, N_ROWS / 128);
    gemm_pass<1><<<grid, 256, 0, stream>>>(ze, emb, arn, brn, packed, ssum, avgp);
    gemm_pass<2><<<grid, 256, 0, stream>>>(ze, emb, arn, brn, packed, ssum, avgp);

    zq_kernel<<<(N_ROWS * (DIM / 4)) / 256, 256, 0, stream>>>(ze, emb, packed, resw, out);
    finalize_kernel<<<1, 256, 0, stream>>>(avgp, resw, out);
}

// Round 2
// 2285.332 us; speedup vs baseline: 2.7439x; 2.7439x over previous
//
#include <hip/hip_runtime.h>
#include <cstdint>
#include <cstddef>

// Problem constants (match reference)
#define N_ROWS 65536
#define K_CODES 4096
#define DIM 512
#define ND_OUT ((size_t)N_ROWS * DIM)   // 33554432

typedef __attribute__((ext_vector_type(8))) short  short8v;   // 8 x bf16 (4 VGPR)
typedef __attribute__((ext_vector_type(4))) float  f32x4;
typedef __attribute__((ext_vector_type(8))) _Float16 half8v;

// ---------------- d_ws layout (bytes) ----------------
#define WS_PACKED   0u            // u64[N]
#define WS_SSUM     524288u       // f32[N]
#define WS_AVGP     786432u       // f32[K]
#define WS_ARN      802816u       // f32[N]
#define WS_BRN      1064960u      // f32[K]
#define WS_PLANES   2097152ull    // bf16 planes: Ah | Al | Bh | Bl (contiguous)
#define SZ_APLANE   67108864ull   // N*512*2
#define SZ_BPLANE   4194304ull    // K*512*2
#define WS_LOGITS   (WS_PLANES + 2*SZ_APLANE + 2*SZ_BPLANE)   // 144703488
#define NEED_B      (WS_LOGITS)
#define NEED_A      (WS_LOGITS + 536870912ull)                // 681574400

// plane offsets in bf16 elements, relative to planes base
#define PE_AH 0
#define PE_AL 33554432
#define PE_BH 67108864
#define PE_BL 69206016

#define GLOAD_LDS16(gsrc, ldst) \
  __builtin_amdgcn_global_load_lds((const __attribute__((address_space(1))) void*)(gsrc), \
                                   (__attribute__((address_space(3))) void*)(ldst), 16, 0, 0)

__device__ inline unsigned long long pack_max(float v, unsigned idx) {
    unsigned u = __float_as_uint(v);
    u = (u & 0x80000000u) ? ~u : (u | 0x80000000u);
    return ((unsigned long long)u << 32) | (unsigned)(~idx);  // tie -> smaller idx wins
}

__device__ inline ushort bf16rn(float f) {
    unsigned u = __float_as_uint(f);
    u += 0x7FFFu + ((u >> 16) & 1u);
    return (ushort)(u >> 16);
}
__device__ inline float bf16f(ushort h) { return __uint_as_float((unsigned)h << 16); }

// ---------------- small prep kernels ----------------

// One wave per row: scale / max(||x||, eps)
__global__ __launch_bounds__(256) void rownorm_kernel(const float* __restrict__ x,
                                                      float* __restrict__ out,
                                                      const float* __restrict__ scale_ptr) {
    int lane = threadIdx.x & 63;
    int row  = blockIdx.x * 4 + (threadIdx.x >> 6);
    const float4* x4 = reinterpret_cast<const float4*>(x) + (size_t)row * (DIM / 4);
    float4 v0 = x4[lane];
    float4 v1 = x4[64 + lane];
    float s = v0.x*v0.x + v0.y*v0.y + v0.z*v0.z + v0.w*v0.w
            + v1.x*v1.x + v1.y*v1.y + v1.z*v1.z + v1.w*v1.w;
#pragma unroll
    for (int off = 32; off; off >>= 1) s += __shfl_xor(s, off);
    if (lane == 0) {
        float scale = scale_ptr ? scale_ptr[0] : 1.0f;
        out[row] = scale / fmaxf(sqrtf(s), 1e-12f);
    }
}

// fp32 -> bf16 hi/lo planes (exact compensated split)
__global__ __launch_bounds__(256) void split_bf16(const float* __restrict__ x,
                                                  ushort* __restrict__ hi,
                                                  ushort* __restrict__ lo, int n4) {
    int i = blockIdx.x * 256 + threadIdx.x;
    if (i >= n4) return;
    float4 v = reinterpret_cast<const float4*>(x)[i];
    ushort4 h, l;
    h.x = bf16rn(v.x); l.x = bf16rn(v.x - bf16f(h.x));
    h.y = bf16rn(v.y); l.y = bf16rn(v.y - bf16f(h.y));
    h.z = bf16rn(v.z); l.z = bf16rn(v.z - bf16f(h.z));
    h.w = bf16rn(v.w); l.w = bf16rn(v.w - bf16f(h.w));
    reinterpret_cast<ushort4*>(hi)[i] = h;
    reinterpret_cast<ushort4*>(lo)[i] = l;
}

// ---------------- MFMA compensated GEMM ----------------
// Block: 256 threads = 4 waves (2x2), tile 256(M) x 128(N), BK=32.
// Wave tile 128x64 = 8x4 fragments of 16x16; 4 MFMA per fragment pair (hi/lo cross terms).
// LDS frag-linear: 16B-unit (rb*64 + lane) holds row rb*16+(lane&15), k-block (lane>>4)*8.
// EPI: 0 = argmax+ssum; 1 = argmax+ssum+store fp16 logits; 2 = avgp (recompute path)
template <int EPI>
__global__ __launch_bounds__(256, 2) void mfma_pass(
        const ushort* __restrict__ planes,
        const float* __restrict__ arn, const float* __restrict__ brn,
        unsigned long long* __restrict__ packed, float* __restrict__ ssum,
        float* __restrict__ avgp, _Float16* __restrict__ logits) {
    __shared__ __align__(16) char lds[49152];   // Ah 16K | Al 16K | Bh 8K | Bl 8K

    const int tid  = threadIdx.x;
    const int lane = tid & 63;
    const int wavei = __builtin_amdgcn_readfirstlane(tid >> 6);
    const int wr = wavei >> 1, wc = wavei & 1;
    const int row0 = blockIdx.y * 256, col0 = blockIdx.x * 128;
    const int r16 = lane & 15, kg = lane >> 4;

    // staging descriptors: 12 global_load_lds per wave per K-step
    int voff[12];    // element offset into planes (per-lane)
    int ldsoff[12];  // byte offset into lds (wave-uniform)
#pragma unroll
    for (int j = 0; j < 12; ++j) {
        int i = wavei + j * 4;
        int rb, lo_, pe, grow;
        if (i < 16)      { rb = i;      lo_ = 0     + rb*1024; pe = PE_AH; grow = row0 + rb*16; }
        else if (i < 32) { rb = i - 16; lo_ = 16384 + rb*1024; pe = PE_AL; grow = row0 + rb*16; }
        else if (i < 40) { rb = i - 32; lo_ = 32768 + rb*1024; pe = PE_BH; grow = col0 + rb*16; }
        else             { rb = i - 40; lo_ = 40960 + rb*1024; pe = PE_BL; grow = col0 + rb*16; }
        voff[j] = pe + (grow + r16) * DIM + kg * 8;
        ldsoff[j] = lo_;
    }

    f32x4 acc[8][4];
#pragma unroll
    for (int m = 0; m < 8; ++m)
#pragma unroll
        for (int n = 0; n < 4; ++n) acc[m][n] = f32x4{0.f, 0.f, 0.f, 0.f};

    const char* lb = (const char*)lds;
    for (int kt = 0; kt < 16; ++kt) {
#pragma unroll
        for (int j = 0; j < 12; ++j)
            GLOAD_LDS16(planes + voff[j] + kt * 32, lds + ldsoff[j]);
        __syncthreads();   // drains vmcnt before LDS reads

        short8v ah[8], al[8], bh[4], bl[4];
#pragma unroll
        for (int m = 0; m < 8; ++m) {
            ah[m] = *(const short8v*)(lb + (wr*8 + m)*1024 + lane*16);
            al[m] = *(const short8v*)(lb + 16384 + (wr*8 + m)*1024 + lane*16);
        }
#pragma unroll
        for (int n = 0; n < 4; ++n) {
            bh[n] = *(const short8v*)(lb + 32768 + (wc*4 + n)*1024 + lane*16);
            bl[n] = *(const short8v*)(lb + 40960 + (wc*4 + n)*1024 + lane*16);
        }
#pragma unroll
        for (int m = 0; m < 8; ++m)
#pragma unroll
            for (int n = 0; n < 4; ++n) {
                acc[m][n] = __builtin_amdgcn_mfma_f32_16x16x32_bf16(ah[m], bh[n], acc[m][n], 0, 0, 0);
                acc[m][n] = __builtin_amdgcn_mfma_f32_16x16x32_bf16(ah[m], bl[n], acc[m][n], 0, 0, 0);
                acc[m][n] = __builtin_amdgcn_mfma_f32_16x16x32_bf16(al[m], bh[n], acc[m][n], 0, 0, 0);
                acc[m][n] = __builtin_amdgcn_mfma_f32_16x16x32_bf16(al[m], bl[n], acc[m][n], 0, 0, 0);
            }
        __syncthreads();
    }

    // ---------------- epilogue ----------------
    const int g = lane >> 4, c15 = lane & 15;
    float bc[4];
#pragma unroll
    for (int n = 0; n < 4; ++n) bc[n] = brn[col0 + wc*64 + n*16 + c15];

    if constexpr (EPI <= 1) {
#pragma unroll
        for (int m = 0; m < 8; ++m)
#pragma unroll
            for (int rr = 0; rr < 4; ++rr) {
                const int grow = row0 + wr*128 + m*16 + g*4 + rr;
                const float ar = arn[grow];
                float mx = -1e30f; int mi = 0; float se = 0.f;
#pragma unroll
                for (int n = 0; n < 4; ++n) {
                    float lg = acc[m][n][rr] * ar * bc[n];
                    int gcol = col0 + wc*64 + n*16 + c15;
                    if constexpr (EPI == 1)
                        logits[(size_t)grow * K_CODES + gcol] = (_Float16)lg;
                    se += __expf(lg);
                    if (lg > mx || (lg == mx && gcol < mi)) { mx = lg; mi = gcol; }
                }
#pragma unroll
                for (int off = 1; off < 16; off <<= 1) {
                    float om = __shfl_xor(mx, off, 16);
                    int   oi = __shfl_xor(mi, off, 16);
                    float os = __shfl_xor(se, off, 16);
                    se += os;
                    if (om > mx || (om == mx && oi < mi)) { mx = om; mi = oi; }
                }
                if (c15 == 0) {
                    atomicMax(packed + grow, pack_max(mx, (unsigned)mi));
                    atomicAdd(&ssum[grow], se);
                }
            }
    } else {
        float cp[4] = {0.f, 0.f, 0.f, 0.f};
#pragma unroll
        for (int m = 0; m < 8; ++m)
#pragma unroll
            for (int rr = 0; rr < 4; ++rr) {
                const int grow = row0 + wr*128 + m*16 + g*4 + rr;
                const float ar = arn[grow];
                const float si = 1.0f / ssum[grow];
#pragma unroll
                for (int n = 0; n < 4; ++n)
                    cp[n] += __expf(acc[m][n][rr] * ar * bc[n]) * si;
            }
#pragma unroll
        for (int n = 0; n < 4; ++n) {
            cp[n] += __shfl_xor(cp[n], 16);
            cp[n] += __shfl_xor(cp[n], 32);
        }
        __syncthreads();
        float* sm = (float*)lds;   // 4 waves x 64 cols
        if (g == 0) {
#pragma unroll
            for (int n = 0; n < 4; ++n) sm[wavei*64 + n*16 + c15] = cp[n];
        }
        __syncthreads();
        if (tid < 128) {
            int wcc = tid >> 6, j = tid & 63;
            float v = sm[wcc*64 + j] + sm[(2 + wcc)*64 + j];
            atomicAdd(&avgp[col0 + wcc*64 + j], v);
        }
    }
}

// Path A pass 2: read stored fp16 logits, accumulate avg_probs (memory-bound)
__global__ __launch_bounds__(256) void avgp_from_logits(const _Float16* __restrict__ lg,
                                                        const float* __restrict__ ssum,
                                                        float* __restrict__ avgp) {
    const int t = threadIdx.x;
    const int rowb = blockIdx.x * 64;
    float cp[16];
#pragma unroll
    for (int j = 0; j < 16; ++j) cp[j] = 0.f;
    for (int rr = 0; rr < 64; ++rr) {
        const float si = 1.0f / ssum[rowb + rr];
        const _Float16* p = lg + (size_t)(rowb + rr) * K_CODES;
#pragma unroll
        for (int j = 0; j < 2; ++j) {
            half8v v = *(const half8v*)(p + j*2048 + t*8);
#pragma unroll
            for (int e = 0; e < 8; ++e)
                cp[j*8 + e] += __expf((float)v[e]) * si;
        }
    }
#pragma unroll
    for (int j = 0; j < 2; ++j)
#pragma unroll
        for (int e = 0; e < 8; ++e)
            atomicAdd(&avgp[j*2048 + t*8 + e], cp[j*8 + e]);
}

// ---------------- Path C fallback: round-1 fp32 VALU GEMM (proven correct) ----------------
template <int PASS>
__global__ __launch_bounds__(256) void gemm_pass(
        const float* __restrict__ A, const float* __restrict__ B,
        const float* __restrict__ arn, const float* __restrict__ brn,
        unsigned long long* __restrict__ packed, float* __restrict__ ssum,
        float* __restrict__ avgp) {
    __shared__ __align__(16) float As[16][132];
    __shared__ __align__(16) float Bs[16][132];
    const int tid = threadIdx.x;
    const int tr = tid >> 4, tc = tid & 15;
    const int row0 = blockIdx.y * 128, col0 = blockIdx.x * 128;

    float acc[8][8] = {};
    const float4* A4 = reinterpret_cast<const float4*>(A);
    const float4* B4 = reinterpret_cast<const float4*>(B);

    for (int d0 = 0; d0 < DIM; d0 += 16) {
#pragma unroll
        for (int l = 0; l < 2; ++l) {
            int q = tid + l * 256;
            int r = q >> 2, dq = q & 3;
            float4 av = A4[(size_t)(row0 + r) * (DIM / 4) + (d0 >> 2) + dq];
            float4 bv = B4[(size_t)(col0 + r) * (DIM / 4) + (d0 >> 2) + dq];
            As[dq*4+0][r] = av.x; As[dq*4+1][r] = av.y; As[dq*4+2][r] = av.z; As[dq*4+3][r] = av.w;
            Bs[dq*4+0][r] = bv.x; Bs[dq*4+1][r] = bv.y; Bs[dq*4+2][r] = bv.z; Bs[dq*4+3][r] = bv.w;
        }
        __syncthreads();
#pragma unroll
        for (int dd = 0; dd < 16; ++dd) {
            float4 a0 = *reinterpret_cast<const float4*>(&As[dd][tr * 4]);
            float4 a1 = *reinterpret_cast<const float4*>(&As[dd][64 + tr * 4]);
            float4 b0 = *reinterpret_cast<const float4*>(&Bs[dd][tc * 4]);
            float4 b1 = *reinterpret_cast<const float4*>(&Bs[dd][64 + tc * 4]);
            float av[8] = {a0.x, a0.y, a0.z, a0.w, a1.x, a1.y, a1.z, a1.w};
            float bv[8] = {b0.x, b0.y, b0.z, b0.w, b1.x, b1.y, b1.z, b1.w};
#pragma unroll
            for (int i = 0; i < 8; ++i)
#pragma unroll
                for (int j = 0; j < 8; ++j)
                    acc[i][j] = fmaf(av[i], bv[j], acc[i][j]);
        }
        __syncthreads();
    }

    int rows[8], cols[8];
    float ar[8], bcv[8];
#pragma unroll
    for (int i = 0; i < 8; ++i) {
        rows[i] = (i < 4) ? (tr * 4 + i) : (64 + tr * 4 + i - 4);
        ar[i] = arn[row0 + rows[i]];
    }
#pragma unroll
    for (int j = 0; j < 8; ++j) {
        cols[j] = (j < 4) ? (tc * 4 + j) : (64 + tc * 4 + j - 4);
        bcv[j] = brn[col0 + cols[j]];
    }

    if constexpr (PASS == 1) {
#pragma unroll
        for (int i = 0; i < 8; ++i) {
            float m = -1e30f; int mi = 0; float se = 0.0f;
#pragma unroll
            for (int j = 0; j < 8; ++j) {
                float l = acc[i][j] * ar[i] * bcv[j];
                int c = col0 + cols[j];
                if (l > m || (l == m && c < mi)) { m = l; mi = c; }
                se += expf(l);
            }
#pragma unroll
            for (int off = 1; off < 16; off <<= 1) {
                float om = __shfl_xor(m, off, 16);
                int   oi = __shfl_xor(mi, off, 16);
                float os = __shfl_xor(se, off, 16);
                se += os;
                if (om > m || (om == m && oi < mi)) { m = om; mi = oi; }
            }
            if (tc == 0) {
                int grow = row0 + rows[i];
                atomicMax(packed + grow, pack_max(m, (unsigned)mi));
                atomicAdd(&ssum[grow], se);
            }
        }
    } else {
        float sinv[8];
#pragma unroll
        for (int i = 0; i < 8; ++i) sinv[i] = 1.0f / ssum[row0 + rows[i]];
        float cp[8] = {};
#pragma unroll
        for (int i = 0; i < 8; ++i)
#pragma unroll
            for (int j = 0; j < 8; ++j)
                cp[j] += expf(acc[i][j] * ar[i] * bcv[j]) * sinv[i];
        __syncthreads();
        float* red = &As[0][0];
#pragma unroll
        for (int j = 0; j < 8; ++j) red[tr * 128 + cols[j]] = cp[j];
        __syncthreads();
        if (tid < 128) {
            float s = 0.0f;
#pragma unroll
            for (int t = 0; t < 16; ++t) s += red[t * 128 + tid];
            atomicAdd(&avgp[col0 + tid], s);
        }
    }
}

// ---------------- output kernels ----------------
__global__ __launch_bounds__(256) void zq_kernel(const float* __restrict__ ze,
                                                 const float* __restrict__ emb,
                                                 const unsigned long long* __restrict__ packed,
                                                 const float* __restrict__ resw,
                                                 float* __restrict__ out) {
    int q = blockIdx.x * 256 + threadIdx.x;
    int n = q >> 7, d4 = q & 127;
    unsigned idx = ~(unsigned)(packed[n] & 0xFFFFFFFFull);
    float alpha = 1.0f / (1.0f + expf(-resw[0]));
    float4 e = reinterpret_cast<const float4*>(emb)[(size_t)idx * 128 + d4];
    float4 z = reinterpret_cast<const float4*>(ze)[(size_t)n * 128 + d4];
    float4 o;
    o.x = alpha * e.x + (1.0f - alpha) * z.x;
    o.y = alpha * e.y + (1.0f - alpha) * z.y;
    o.z = alpha * e.z + (1.0f - alpha) * z.z;
    o.w = alpha * e.w + (1.0f - alpha) * z.w;
    reinterpret_cast<float4*>(out)[(size_t)n * 128 + d4] = o;
    if (d4 == 0) out[ND_OUT + n] = (float)idx;
}

__global__ __launch_bounds__(256) void finalize_kernel(const float* __restrict__ avgp,
                                                       const float* __restrict__ resw,
                                                       float* __restrict__ out) {
    float acc = 0.0f;
    for (int k = threadIdx.x; k < K_CODES; k += 256) {
        float p = avgp[k] * (1.0f / (float)N_ROWS);
        acc += p * logf(p + 1e-10f);
    }
    __shared__ float red[4];
#pragma unroll
    for (int off = 32; off; off >>= 1) acc += __shfl_xor(acc, off);
    int lane = threadIdx.x & 63, wave = threadIdx.x >> 6;
    if (lane == 0) red[wave] = acc;
    __syncthreads();
    if (threadIdx.x == 0) {
        float s = red[0] + red[1] + red[2] + red[3];
        out[ND_OUT + N_ROWS]     = expf(-s);
        out[ND_OUT + N_ROWS + 1] = 1.0f / (1.0f + expf(-resw[0]));
    }
}

extern "C" void kernel_launch(void* const* d_in, const int* in_sizes, int n_in,
                              void* d_out, int out_size, void* d_ws, size_t ws_size,
                              hipStream_t stream) {
    const float* ze   = (const float*)d_in[0];
    const float* emb  = (const float*)d_in[1];
    const float* ls   = (const float*)d_in[2];
    const float* resw = (const float*)d_in[3];
    float* out = (float*)d_out;

    char* ws = (char*)d_ws;
    unsigned long long* packed = (unsigned long long*)(ws + WS_PACKED);
    float* ssum = (float*)(ws + WS_SSUM);
    float* avgp = (float*)(ws + WS_AVGP);
    float* arn  = (float*)(ws + WS_ARN);
    float* brn  = (float*)(ws + WS_BRN);

    hipMemsetAsync(d_ws, 0, 802816, stream);   // packed | ssum | avgp

    rownorm_kernel<<<N_ROWS / 4, 256, 0, stream>>>(ze, arn, ls);
    rownorm_kernel<<<K_CODES / 4, 256, 0, stream>>>(emb, brn, nullptr);

    if (ws_size >= NEED_B) {
        ushort* planes = (ushort*)(ws + WS_PLANES);
        _Float16* logits = (_Float16*)(ws + WS_LOGITS);
        split_bf16<<<(N_ROWS * DIM / 4) / 256, 256, 0, stream>>>(ze, planes + PE_AH, planes + PE_AL, N_ROWS * DIM / 4);
        split_bf16<<<(K_CODES * DIM / 4) / 256, 256, 0, stream>>>(emb, planes + PE_BH, planes + PE_BL, K_CODES * DIM / 4);

        dim3 grid(K_CODES / 128, N_ROWS / 256);
        if (ws_size >= NEED_A) {
            mfma_pass<1><<<grid, 256, 0, stream>>>(planes, arn, brn, packed, ssum, avgp, logits);
            avgp_from_logits<<<N_ROWS / 64, 256, 0, stream>>>(logits, ssum, avgp);
        } else {
            mfma_pass<0><<<grid, 256, 0, stream>>>(planes, arn, brn, packed, ssum, avgp, nullptr);
            mfma_pass<2><<<grid, 256, 0, stream>>>(planes, arn, brn, packed, ssum, avgp, nullptr);
        }
    } else {
        dim3 grid(K_CODES / 128, N_ROWS / 128);
        gemm_pass<1><<<grid, 256, 0, stream>>>(ze, emb, arn, brn, packed, ssum, avgp);
        gemm_pass<2><<<grid, 256, 0, stream>>>(ze, emb, arn, brn, packed, ssum, avgp);
    }

    zq_kernel<<<(N_ROWS * (DIM / 4)) / 256, 256, 0, stream>>>(ze, emb, packed, resw, out);
    finalize_kernel<<<1, 256, 0, stream>>>(avgp, resw, out);
}

// Round 3
// 1514.265 us; speedup vs baseline: 4.1411x; 1.5092x over previous
//
#include <hip/hip_runtime.h>
#include <cstdint>
#include <cstddef>

// Problem constants (match reference)
#define N_ROWS 65536
#define K_CODES 4096
#define DIM 512
#define ND_OUT ((size_t)N_ROWS * DIM)   // 33554432

typedef __attribute__((ext_vector_type(8))) short  short8v;   // 8 x bf16 (4 VGPR)
typedef __attribute__((ext_vector_type(4))) float  f32x4;

// ---------------- d_ws layout (bytes) ----------------
#define WS_PACKED   0u            // u64[N]
#define WS_SSUM     524288u       // f32[N]
#define WS_AVGP     786432u       // f32[K]
#define WS_ARN      802816u       // f32[N]
#define WS_BRN      1064960u      // f32[K]
#define WS_PLANES   2097152ull    // bf16 planes: Ah | Al | Bh | Bl (contiguous)
#define SZ_APLANE   67108864ull   // N*512*2
#define SZ_BPLANE   4194304ull    // K*512*2
#define NEED_B      (WS_PLANES + 2*SZ_APLANE + 2*SZ_BPLANE)   // 144703488

// plane offsets in bf16 elements, relative to planes base
#define PE_AH 0
#define PE_AL 33554432
#define PE_BH 67108864
#define PE_BL 69206016

#define GLOAD_LDS16(gsrc, ldst) \
  __builtin_amdgcn_global_load_lds((const __attribute__((address_space(1))) void*)(gsrc), \
                                   (__attribute__((address_space(3))) void*)(ldst), 16, 0, 0)

__device__ inline unsigned long long pack_max(float v, unsigned idx) {
    unsigned u = __float_as_uint(v);
    u = (u & 0x80000000u) ? ~u : (u | 0x80000000u);
    return ((unsigned long long)u << 32) | (unsigned)(~idx);  // tie -> smaller idx wins
}

__device__ inline ushort bf16rn(float f) {
    unsigned u = __float_as_uint(f);
    u += 0x7FFFu + ((u >> 16) & 1u);
    return (ushort)(u >> 16);
}
__device__ inline float bf16f(ushort h) { return __uint_as_float((unsigned)h << 16); }

// ---------------- small prep kernels ----------------

__global__ __launch_bounds__(256) void rownorm_kernel(const float* __restrict__ x,
                                                      float* __restrict__ out,
                                                      const float* __restrict__ scale_ptr) {
    int lane = threadIdx.x & 63;
    int row  = blockIdx.x * 4 + (threadIdx.x >> 6);
    const float4* x4 = reinterpret_cast<const float4*>(x) + (size_t)row * (DIM / 4);
    float4 v0 = x4[lane];
    float4 v1 = x4[64 + lane];
    float s = v0.x*v0.x + v0.y*v0.y + v0.z*v0.z + v0.w*v0.w
            + v1.x*v1.x + v1.y*v1.y + v1.z*v1.z + v1.w*v1.w;
#pragma unroll
    for (int off = 32; off; off >>= 1) s += __shfl_xor(s, off);
    if (lane == 0) {
        float scale = scale_ptr ? scale_ptr[0] : 1.0f;
        out[row] = scale / fmaxf(sqrtf(s), 1e-12f);
    }
}

__global__ __launch_bounds__(256) void split_bf16(const float* __restrict__ x,
                                                  ushort* __restrict__ hi,
                                                  ushort* __restrict__ lo, int n4) {
    int i = blockIdx.x * 256 + threadIdx.x;
    if (i >= n4) return;
    float4 v = reinterpret_cast<const float4*>(x)[i];
    ushort4 h, l;
    h.x = bf16rn(v.x); l.x = bf16rn(v.x - bf16f(h.x));
    h.y = bf16rn(v.y); l.y = bf16rn(v.y - bf16f(h.y));
    h.z = bf16rn(v.z); l.z = bf16rn(v.z - bf16f(h.z));
    h.w = bf16rn(v.w); l.w = bf16rn(v.w - bf16f(h.w));
    reinterpret_cast<ushort4*>(hi)[i] = h;
    reinterpret_cast<ushort4*>(lo)[i] = l;
}

// ---------------- 2-phase double-buffered MFMA GEMM ----------------
// Tile 256(M) x 256(N), BK=32, 512 threads = 8 waves (4 wr x 2 wc), wave-tile 64x128.
// LDS buffer (TERMS=4): [Ah 16u | Al 16u | Bh 16u | Bl 16u] x 1KB units; dbuf 2x64KB.
//     (TERMS=1): [Ah 16u | Bh 16u]; dbuf 2x32KB.
// Unit u = 16-row x 32-k frag-block: lane l holds row (l&15), k=(l>>4)*8..+8 (MFMA A/B frag).
// EPI 0: argmax + sumexp (pass 1, exact 4-term). EPI 2: avg_probs accumulate (pass 2, hh-only).
template <int EPI, int TERMS>
__global__ __launch_bounds__(512, 2) void mfma2(
        const ushort* __restrict__ planes,
        const float* __restrict__ arn, const float* __restrict__ brn,
        unsigned long long* __restrict__ packed, float* __restrict__ ssum,
        float* __restrict__ avgp) {
    constexpr int BUFSZ = (TERMS == 4) ? 65536 : 32768;
    constexpr int BHOFF = (TERMS == 4) ? 32768 : 16384;
    constexpr int NST   = (TERMS == 4) ? 8 : 4;
    __shared__ __align__(16) char buf0[BUFSZ];
    __shared__ __align__(16) char buf1[BUFSZ];

    const int tid  = threadIdx.x;
    const int lane = tid & 63;
    const int wavei = __builtin_amdgcn_readfirstlane(tid >> 6);
    const int wr = wavei >> 1, wc = wavei & 1;
    const int r16 = lane & 15, kg = lane >> 4;

    // XCD-aware swizzle: nwg=4096 (%8==0), chunk of 512 per XCD; bx fastest so the
    // 16 col-blocks sharing one A row-panel run on the same XCD's L2.
    const int orig = blockIdx.x;
    const int swz  = (orig & 7) * 512 + (orig >> 3);
    const int row0 = (swz >> 4) * 256, col0 = (swz & 15) * 256;

    // staging descriptors: NST units per wave per K-step (unit = 64 lanes x 16B)
    const ushort* gsrc[NST];
    int ldsu[NST];
#pragma unroll
    for (int j = 0; j < NST; ++j) {
        int u = wavei * NST + j;
        int p = u >> 4, rb = u & 15;
        int pe, g0;
        if constexpr (TERMS == 4) {
            pe = (p == 0) ? PE_AH : (p == 1) ? PE_AL : (p == 2) ? PE_BH : PE_BL;
            g0 = (p < 2) ? row0 : col0;
        } else {
            pe = (p == 0) ? PE_AH : PE_BH;
            g0 = (p == 0) ? row0 : col0;
        }
        gsrc[j] = planes + pe + (size_t)(g0 + rb * 16 + r16) * DIM + kg * 8;
        ldsu[j] = u * 1024;
    }

    f32x4 acc[4][8];
#pragma unroll
    for (int m = 0; m < 4; ++m)
#pragma unroll
        for (int n = 0; n < 8; ++n) acc[m][n] = f32x4{0.f, 0.f, 0.f, 0.f};

#define MFMA_STEP(CUR, NXT, KT)                                                       \
    {                                                                                  \
        if ((KT) + 1 < 16) {                                                           \
            _Pragma("unroll")                                                          \
            for (int j = 0; j < NST; ++j)                                              \
                GLOAD_LDS16(gsrc[j] + ((KT) + 1) * 32, (char*)(NXT) + ldsu[j]);        \
        }                                                                              \
        short8v ah[4], al[4];                                                          \
        _Pragma("unroll")                                                              \
        for (int m = 0; m < 4; ++m) {                                                  \
            ah[m] = *(const short8v*)((CUR) + (wr * 4 + m) * 1024 + lane * 16);        \
            if constexpr (TERMS == 4)                                                  \
                al[m] = *(const short8v*)((CUR) + 16384 + (wr * 4 + m) * 1024 + lane * 16); \
        }                                                                              \
        __builtin_amdgcn_s_setprio(1);                                                 \
        _Pragma("unroll")                                                              \
        for (int nh = 0; nh < 2; ++nh) {                                               \
            short8v bh[4], bl[4];                                                      \
            _Pragma("unroll")                                                          \
            for (int n = 0; n < 4; ++n) {                                              \
                int nn = nh * 4 + n;                                                   \
                bh[n] = *(const short8v*)((CUR) + BHOFF + (wc * 8 + nn) * 1024 + lane * 16); \
                if constexpr (TERMS == 4)                                              \
                    bl[n] = *(const short8v*)((CUR) + 49152 + (wc * 8 + nn) * 1024 + lane * 16); \
            }                                                                          \
            _Pragma("unroll")                                                          \
            for (int m = 0; m < 4; ++m)                                                \
                _Pragma("unroll")                                                      \
                for (int n = 0; n < 4; ++n) {                                          \
                    int nn = nh * 4 + n;                                               \
                    acc[m][nn] = __builtin_amdgcn_mfma_f32_16x16x32_bf16(ah[m], bh[n], acc[m][nn], 0, 0, 0); \
                    if constexpr (TERMS == 4) {                                        \
                        acc[m][nn] = __builtin_amdgcn_mfma_f32_16x16x32_bf16(ah[m], bl[n], acc[m][nn], 0, 0, 0); \
                        acc[m][nn] = __builtin_amdgcn_mfma_f32_16x16x32_bf16(al[m], bh[n], acc[m][nn], 0, 0, 0); \
                        acc[m][nn] = __builtin_amdgcn_mfma_f32_16x16x32_bf16(al[m], bl[n], acc[m][nn], 0, 0, 0); \
                    }                                                                  \
                }                                                                      \
        }                                                                              \
        __builtin_amdgcn_s_setprio(0);                                                 \
        __syncthreads();                                                               \
    }

    // prologue: stage K-step 0 into buf0, drain, barrier
#pragma unroll
    for (int j = 0; j < NST; ++j)
        GLOAD_LDS16(gsrc[j], (char*)buf0 + ldsu[j]);
    __syncthreads();

#pragma unroll 1
    for (int kt = 0; kt < 16; kt += 2) {
        MFMA_STEP(buf0, buf1, kt);
        MFMA_STEP(buf1, buf0, kt + 1);
    }
#undef MFMA_STEP

    // ---------------- epilogue ----------------
    const int g = lane >> 4, c15 = lane & 15;
    float bc[8];
#pragma unroll
    for (int n = 0; n < 8; ++n) bc[n] = brn[col0 + wc * 128 + n * 16 + c15];

    if constexpr (EPI == 0) {
#pragma unroll
        for (int m = 0; m < 4; ++m)
#pragma unroll
            for (int rr = 0; rr < 4; ++rr) {
                const int grow = row0 + wr * 64 + m * 16 + g * 4 + rr;
                const float ar = arn[grow];
                float mx = -1e30f; int mi = 0; float se = 0.f;
#pragma unroll
                for (int n = 0; n < 8; ++n) {
                    float lg = acc[m][n][rr] * ar * bc[n];
                    int gcol = col0 + wc * 128 + n * 16 + c15;
                    se += __expf(lg);
                    if (lg > mx || (lg == mx && gcol < mi)) { mx = lg; mi = gcol; }
                }
#pragma unroll
                for (int off = 1; off < 16; off <<= 1) {
                    float om = __shfl_xor(mx, off, 16);
                    int   oi = __shfl_xor(mi, off, 16);
                    float os = __shfl_xor(se, off, 16);
                    se += os;
                    if (om > mx || (om == mx && oi < mi)) { mx = om; mi = oi; }
                }
                if (c15 == 0) {
                    atomicMax(packed + grow, pack_max(mx, (unsigned)mi));
                    atomicAdd(&ssum[grow], se);
                }
            }
    } else {
        float cp[8] = {0.f, 0.f, 0.f, 0.f, 0.f, 0.f, 0.f, 0.f};
#pragma unroll
        for (int m = 0; m < 4; ++m)
#pragma unroll
            for (int rr = 0; rr < 4; ++rr) {
                const int grow = row0 + wr * 64 + m * 16 + g * 4 + rr;
                const float ar = arn[grow];
                const float si = 1.0f / ssum[grow];
#pragma unroll
                for (int n = 0; n < 8; ++n)
                    cp[n] += __expf(acc[m][n][rr] * ar * bc[n]) * si;
            }
#pragma unroll
        for (int n = 0; n < 8; ++n) {
            cp[n] += __shfl_xor(cp[n], 16);
            cp[n] += __shfl_xor(cp[n], 32);
        }
        float* sm = (float*)buf0;   // free after final barrier
        if (g == 0) {
#pragma unroll
            for (int n = 0; n < 8; ++n) sm[wavei * 128 + n * 16 + c15] = cp[n];
        }
        __syncthreads();
        if (tid < 256) {
            int wcc = tid >> 7, j = tid & 127;
            float s = sm[(0 + wcc) * 128 + j] + sm[(2 + wcc) * 128 + j]
                    + sm[(4 + wcc) * 128 + j] + sm[(6 + wcc) * 128 + j];
            atomicAdd(&avgp[col0 + wcc * 128 + j], s);
        }
    }
}

// ---------------- fallback: fp32 VALU GEMM (proven round-1 path) ----------------
template <int PASS>
__global__ __launch_bounds__(256) void gemm_pass(
        const float* __restrict__ A, const float* __restrict__ B,
        const float* __restrict__ arn, const float* __restrict__ brn,
        unsigned long long* __restrict__ packed, float* __restrict__ ssum,
        float* __restrict__ avgp) {
    __shared__ __align__(16) float As[16][132];
    __shared__ __align__(16) float Bs[16][132];
    const int tid = threadIdx.x;
    const int tr = tid >> 4, tc = tid & 15;
    const int row0 = blockIdx.y * 128, col0 = blockIdx.x * 128;

    float acc[8][8] = {};
    const float4* A4 = reinterpret_cast<const float4*>(A);
    const float4* B4 = reinterpret_cast<const float4*>(B);

    for (int d0 = 0; d0 < DIM; d0 += 16) {
#pragma unroll
        for (int l = 0; l < 2; ++l) {
            int q = tid + l * 256;
            int r = q >> 2, dq = q & 3;
            float4 av = A4[(size_t)(row0 + r) * (DIM / 4) + (d0 >> 2) + dq];
            float4 bv = B4[(size_t)(col0 + r) * (DIM / 4) + (d0 >> 2) + dq];
            As[dq*4+0][r] = av.x; As[dq*4+1][r] = av.y; As[dq*4+2][r] = av.z; As[dq*4+3][r] = av.w;
            Bs[dq*4+0][r] = bv.x; Bs[dq*4+1][r] = bv.y; Bs[dq*4+2][r] = bv.z; Bs[dq*4+3][r] = bv.w;
        }
        __syncthreads();
#pragma unroll
        for (int dd = 0; dd < 16; ++dd) {
            float4 a0 = *reinterpret_cast<const float4*>(&As[dd][tr * 4]);
            float4 a1 = *reinterpret_cast<const float4*>(&As[dd][64 + tr * 4]);
            float4 b0 = *reinterpret_cast<const float4*>(&Bs[dd][tc * 4]);
            float4 b1 = *reinterpret_cast<const float4*>(&Bs[dd][64 + tc * 4]);
            float av[8] = {a0.x, a0.y, a0.z, a0.w, a1.x, a1.y, a1.z, a1.w};
            float bv[8] = {b0.x, b0.y, b0.z, b0.w, b1.x, b1.y, b1.z, b1.w};
#pragma unroll
            for (int i = 0; i < 8; ++i)
#pragma unroll
                for (int j = 0; j < 8; ++j)
                    acc[i][j] = fmaf(av[i], bv[j], acc[i][j]);
        }
        __syncthreads();
    }

    int rows[8], cols[8];
    float ar[8], bcv[8];
#pragma unroll
    for (int i = 0; i < 8; ++i) {
        rows[i] = (i < 4) ? (tr * 4 + i) : (64 + tr * 4 + i - 4);
        ar[i] = arn[row0 + rows[i]];
    }
#pragma unroll
    for (int j = 0; j < 8; ++j) {
        cols[j] = (j < 4) ? (tc * 4 + j) : (64 + tc * 4 + j - 4);
        bcv[j] = brn[col0 + cols[j]];
    }

    if constexpr (PASS == 1) {
#pragma unroll
        for (int i = 0; i < 8; ++i) {
            float m = -1e30f; int mi = 0; float se = 0.0f;
#pragma unroll
            for (int j = 0; j < 8; ++j) {
                float l = acc[i][j] * ar[i] * bcv[j];
                int c = col0 + cols[j];
                if (l > m || (l == m && c < mi)) { m = l; mi = c; }
                se += expf(l);
            }
#pragma unroll
            for (int off = 1; off < 16; off <<= 1) {
                float om = __shfl_xor(m, off, 16);
                int   oi = __shfl_xor(mi, off, 16);
                float os = __shfl_xor(se, off, 16);
                se += os;
                if (om > m || (om == m && oi < mi)) { m = om; mi = oi; }
            }
            if (tc == 0) {
                int grow = row0 + rows[i];
                atomicMax(packed + grow, pack_max(m, (unsigned)mi));
                atomicAdd(&ssum[grow], se);
            }
        }
    } else {
        float sinv[8];
#pragma unroll
        for (int i = 0; i < 8; ++i) sinv[i] = 1.0f / ssum[row0 + rows[i]];
        float cp[8] = {};
#pragma unroll
        for (int i = 0; i < 8; ++i)
#pragma unroll
            for (int j = 0; j < 8; ++j)
                cp[j] += expf(acc[i][j] * ar[i] * bcv[j]) * sinv[i];
        __syncthreads();
        float* red = &As[0][0];
#pragma unroll
        for (int j = 0; j < 8; ++j) red[tr * 128 + cols[j]] = cp[j];
        __syncthreads();
        if (tid < 128) {
            float s = 0.0f;
#pragma unroll
            for (int t = 0; t < 16; ++t) s += red[t * 128 + tid];
            atomicAdd(&avgp[col0 + tid], s);
        }
    }
}

// ---------------- output kernels ----------------
__global__ __launch_bounds__(256) void zq_kernel(const float* __restrict__ ze,
                                                 const float* __restrict__ emb,
                                                 const unsigned long long* __restrict__ packed,
                                                 const float* __restrict__ resw,
                                                 float* __restrict__ out) {
    int q = blockIdx.x * 256 + threadIdx.x;
    int n = q >> 7, d4 = q & 127;
    unsigned idx = ~(unsigned)(packed[n] & 0xFFFFFFFFull);
    float alpha = 1.0f / (1.0f + expf(-resw[0]));
    float4 e = reinterpret_cast<const float4*>(emb)[(size_t)idx * 128 + d4];
    float4 z = reinterpret_cast<const float4*>(ze)[(size_t)n * 128 + d4];
    float4 o;
    o.x = alpha * e.x + (1.0f - alpha) * z.x;
    o.y = alpha * e.y + (1.0f - alpha) * z.y;
    o.z = alpha * e.z + (1.0f - alpha) * z.z;
    o.w = alpha * e.w + (1.0f - alpha) * z.w;
    reinterpret_cast<float4*>(out)[(size_t)n * 128 + d4] = o;
    if (d4 == 0) out[ND_OUT + n] = (float)idx;
}

__global__ __launch_bounds__(256) void finalize_kernel(const float* __restrict__ avgp,
                                                       const float* __restrict__ resw,
                                                       float* __restrict__ out) {
    float acc = 0.0f;
    for (int k = threadIdx.x; k < K_CODES; k += 256) {
        float p = avgp[k] * (1.0f / (float)N_ROWS);
        acc += p * logf(p + 1e-10f);
    }
    __shared__ float red[4];
#pragma unroll
    for (int off = 32; off; off >>= 1) acc += __shfl_xor(acc, off);
    int lane = threadIdx.x & 63, wave = threadIdx.x >> 6;
    if (lane == 0) red[wave] = acc;
    __syncthreads();
    if (threadIdx.x == 0) {
        float s = red[0] + red[1] + red[2] + red[3];
        out[ND_OUT + N_ROWS]     = expf(-s);
        out[ND_OUT + N_ROWS + 1] = 1.0f / (1.0f + expf(-resw[0]));
    }
}

extern "C" void kernel_launch(void* const* d_in, const int* in_sizes, int n_in,
                              void* d_out, int out_size, void* d_ws, size_t ws_size,
                              hipStream_t stream) {
    const float* ze   = (const float*)d_in[0];
    const float* emb  = (const float*)d_in[1];
    const float* ls   = (const float*)d_in[2];
    const float* resw = (const float*)d_in[3];
    float* out = (float*)d_out;

    char* ws = (char*)d_ws;
    unsigned long long* packed = (unsigned long long*)(ws + WS_PACKED);
    float* ssum = (float*)(ws + WS_SSUM);
    float* avgp = (float*)(ws + WS_AVGP);
    float* arn  = (float*)(ws + WS_ARN);
    float* brn  = (float*)(ws + WS_BRN);

    hipMemsetAsync(d_ws, 0, 802816, stream);   // packed | ssum | avgp

    rownorm_kernel<<<N_ROWS / 4, 256, 0, stream>>>(ze, arn, ls);
    rownorm_kernel<<<K_CODES / 4, 256, 0, stream>>>(emb, brn, nullptr);

    if (ws_size >= NEED_B) {
        ushort* planes = (ushort*)(ws + WS_PLANES);
        split_bf16<<<(N_ROWS * DIM / 4) / 256, 256, 0, stream>>>(ze, planes + PE_AH, planes + PE_AL, N_ROWS * DIM / 4);
        split_bf16<<<(K_CODES * DIM / 4) / 256, 256, 0, stream>>>(emb, planes + PE_BH, planes + PE_BL, K_CODES * DIM / 4);

        // pass 1: exact 4-term compensated GEMM -> argmax + sumexp
        mfma2<0, 4><<<4096, 512, 0, stream>>>(planes, arn, brn, packed, ssum, avgp);
        // pass 2: hi*hi only (avg_probs tolerates ~5% per-element exp error)
        mfma2<2, 1><<<4096, 512, 0, stream>>>(planes, arn, brn, packed, ssum, avgp);
    } else {
        dim3 grid(K_CODES / 128, N_ROWS / 128);
        gemm_pass<1><<<grid, 256, 0, stream>>>(ze, emb, arn, brn, packed, ssum, avgp);
        gemm_pass<2><<<grid, 256, 0, stream>>>(ze, emb, arn, brn, packed, ssum, avgp);
    }

    zq_kernel<<<(N_ROWS * (DIM / 4)) / 256, 256, 0, stream>>>(ze, emb, packed, resw, out);
    finalize_kernel<<<1, 256, 0, stream>>>(avgp, resw, out);
}